// Round 4
// baseline (626.033 us; speedup 1.0000x reference)
//
#include <hip/hip_runtime.h>

#define NN 100000
#define NE 1600000
#define C 32
#define SCAN_T 1024
#define CHUNK ((NN + SCAN_T - 1) / SCAN_T)  // 98

// ---------------- kernels ----------------

__global__ void k_zero(int* __restrict__ cnt) {
    int i = blockIdx.x * blockDim.x + threadIdx.x;
    if (i < NN) cnt[i] = 0;
}

// integer in-degree histogram (excludes self-loop)
__global__ void k_hist(const int* __restrict__ ei, int* __restrict__ cnt) {
    int e = blockIdx.x * blockDim.x + threadIdx.x;
    if (e < NE) atomicAdd(&cnt[ei[NE + e]], 1);
}

// single-block exclusive scan of cnt -> off, cur; dinv = rsqrt(1+cnt)
__global__ __launch_bounds__(SCAN_T) void k_scan(const int* __restrict__ cnt,
                                                 int* __restrict__ off,
                                                 int* __restrict__ cur,
                                                 float* __restrict__ dinv) {
    __shared__ int ps[SCAN_T];
    int t = threadIdx.x;
    int start = t * CHUNK, end = min(start + CHUNK, NN);
    int sum = 0;
    for (int i = start; i < end; ++i) sum += cnt[i];
    ps[t] = sum;
    __syncthreads();
    for (int d = 1; d < SCAN_T; d <<= 1) {   // Hillis-Steele inclusive scan
        int v = (t >= d) ? ps[t - d] : 0;
        __syncthreads();
        ps[t] += v;
        __syncthreads();
    }
    int running = ps[t] - sum;               // exclusive base for this chunk
    for (int i = start; i < end; ++i) {
        int cv = cnt[i];
        off[i] = running;
        cur[i] = running;
        dinv[i] = rsqrtf(1.0f + (float)cv);  // deg includes self-loop
        running += cv;
    }
    if (start < NN && end == NN) off[NN] = running;  // == NE
}

// bucket edges by target: srt[off[col]..off[col+1]) = source ids
__global__ void k_sort(const int* __restrict__ ei, int* __restrict__ cur,
                       int* __restrict__ srt) {
    int e = blockIdx.x * blockDim.x + threadIdx.x;
    if (e < NE) {
        int rw = ei[e], cl = ei[NE + e];
        int pos = atomicAdd(&cur[cl], 1);
        srt[pos] = rw;
    }
}

// h = x @ W^T  (into ws)
__global__ void k_linear(const float* __restrict__ x,
                         const float* __restrict__ W,
                         float* __restrict__ h) {
    __shared__ float Ws[C][C + 1];
    __shared__ float xs[8][C];
    int t = threadIdx.x;            // 0..255
    for (int i = t; i < C * C; i += 256)
        Ws[i / C][i % C] = W[i];

    int node0 = blockIdx.x * 8;
    int lnode = t >> 5;             // 0..7
    int cout  = t & 31;
    int node  = node0 + lnode;
    {
        int idx = node0 * C + t;    // coalesced load of 8 rows
        xs[lnode][cout] = (idx < NN * C) ? x[idx] : 0.0f;
    }
    __syncthreads();
    if (node < NN) {
        float s = 0.0f;
#pragma unroll
        for (int k = 0; k < C; ++k) s += xs[lnode][k] * Ws[cout][k];
        h[node * C + cout] = s;
    }
}

// one 64-lane wave per node: segmented sum over its bucketed edges,
// + bias + self-loop, single coalesced row store. No atomics.
__global__ __launch_bounds__(256) void k_agg(const int* __restrict__ off,
                                             const int* __restrict__ srt,
                                             const float* __restrict__ h,
                                             const float* __restrict__ dinv,
                                             const float* __restrict__ b,
                                             float* __restrict__ out) {
    int n = (blockIdx.x * blockDim.x + threadIdx.x) >> 6;
    if (n >= NN) return;
    int lane = threadIdx.x & 63;
    int c = lane & 31, p = lane >> 5;        // 2 edges in flight per wave
    int beg = off[n], end = off[n + 1];
    float s = 0.0f;
    for (int j = beg + p; j < end; j += 2) {
        int r = srt[j];                      // broadcast across 32 lanes
        s += h[r * C + c] * dinv[r];         // 128B coalesced row gather
    }
    s += __shfl_xor(s, 32);                  // combine p=0 / p=1 partials
    if (p == 0) {
        float dn = dinv[n];
        out[n * C + c] = b[c] + dn * (s + dn * h[n * C + c]);
    }
}

// ---------------- launch ----------------

extern "C" void kernel_launch(void* const* d_in, const int* in_sizes, int n_in,
                              void* d_out, int out_size, void* d_ws, size_t ws_size,
                              hipStream_t stream) {
    const float* x  = (const float*)d_in[0];
    const int*   ei = (const int*)d_in[1];
    const float* W  = (const float*)d_in[2];
    const float* b  = (const float*)d_in[3];
    float* out = (float*)d_out;

    // workspace layout (~20.8 MB), 256B-aligned slices
    char* ws = (char*)d_ws;
    size_t o = 0;
    float* h    = (float*)(ws + o); o += (size_t)NN * C * 4;      o = (o + 255) & ~(size_t)255;
    int*   cnt  = (int*)(ws + o);   o += (size_t)NN * 4;          o = (o + 255) & ~(size_t)255;
    int*   off  = (int*)(ws + o);   o += (size_t)(NN + 1) * 4;    o = (o + 255) & ~(size_t)255;
    int*   cur  = (int*)(ws + o);   o += (size_t)NN * 4;          o = (o + 255) & ~(size_t)255;
    float* dinv = (float*)(ws + o); o += (size_t)NN * 4;          o = (o + 255) & ~(size_t)255;
    int*   srt  = (int*)(ws + o);

    k_zero<<<(NN + 255) / 256, 256, 0, stream>>>(cnt);
    k_hist<<<(NE + 255) / 256, 256, 0, stream>>>(ei, cnt);
    k_scan<<<1, SCAN_T, 0, stream>>>(cnt, off, cur, dinv);
    k_sort<<<(NE + 255) / 256, 256, 0, stream>>>(ei, cur, srt);
    k_linear<<<(NN + 7) / 8, 256, 0, stream>>>(x, W, h);
    k_agg<<<(NN * 64 + 255) / 256, 256, 0, stream>>>(off, srt, h, dinv, b, out);
}

// Round 5
// 371.381 us; speedup vs baseline: 1.6857x; 1.6857x over previous
//
#include <hip/hip_runtime.h>

#define NN 100000
#define NE 1600000
#define C 32
#define TILE 2048
#define NSCB ((NN + TILE - 1) / TILE)   // 49 scan blocks

// ---------------- kernels ----------------

__global__ void k_zero(int* __restrict__ cnt) {
    int i = blockIdx.x * blockDim.x + threadIdx.x;
    if (i < NN) cnt[i] = 0;
}

// integer in-degree histogram (excludes self-loop)
__global__ void k_hist(const int* __restrict__ ei, int* __restrict__ cnt) {
    int e = blockIdx.x * blockDim.x + threadIdx.x;
    if (e < NE) atomicAdd(&cnt[ei[NE + e]], 1);
}

// phase 1: per-tile sums (coalesced)
__global__ __launch_bounds__(256) void k_psum(const int* __restrict__ cnt,
                                              int* __restrict__ bsum) {
    int base = blockIdx.x * TILE;
    int s = 0;
    for (int i = threadIdx.x; i < TILE; i += 256) {
        int idx = base + i;
        if (idx < NN) s += cnt[idx];
    }
#pragma unroll
    for (int d = 32; d; d >>= 1) s += __shfl_down(s, d);
    __shared__ int wsum[4];
    if ((threadIdx.x & 63) == 0) wsum[threadIdx.x >> 6] = s;
    __syncthreads();
    if (threadIdx.x == 0) bsum[blockIdx.x] = wsum[0] + wsum[1] + wsum[2] + wsum[3];
}

// phase 2: one wave scans the 49 tile sums -> exclusive tile offsets
__global__ __launch_bounds__(64) void k_bscan(const int* __restrict__ bsum,
                                              int* __restrict__ boff) {
    int t = threadIdx.x;
    int orig = (t < NSCB) ? bsum[t] : 0;
    int v = orig;
#pragma unroll
    for (int d = 1; d < 64; d <<= 1) {
        int u = __shfl_up(v, d);
        if (t >= d) v += u;
    }
    if (t < NSCB) boff[t] = v - orig;  // exclusive
}

// phase 3: per-tile exclusive scan, write off/cur/dinv
__global__ __launch_bounds__(256) void k_fin(const int* __restrict__ cnt,
                                             const int* __restrict__ boff,
                                             int* __restrict__ off,
                                             int* __restrict__ cur,
                                             float* __restrict__ dinv) {
    __shared__ int ts[256];
    int t = threadIdx.x;
    int s0 = blockIdx.x * TILE + t * 8;   // 8 contiguous elems per thread
    int v[8];
    int sum = 0;
#pragma unroll
    for (int k = 0; k < 8; ++k) {
        int idx = s0 + k;
        v[k] = (idx < NN) ? cnt[idx] : 0;
        sum += v[k];
    }
    ts[t] = sum;
    __syncthreads();
    for (int d = 1; d < 256; d <<= 1) {   // Hillis-Steele inclusive
        int u = (t >= d) ? ts[t - d] : 0;
        __syncthreads();
        ts[t] += u;
        __syncthreads();
    }
    int run = boff[blockIdx.x] + ts[t] - sum;  // exclusive prefix
#pragma unroll
    for (int k = 0; k < 8; ++k) {
        int idx = s0 + k;
        if (idx < NN) {
            off[idx] = run;
            cur[idx] = run;
            dinv[idx] = rsqrtf(1.0f + (float)v[k]);  // deg incl. self-loop
        }
        run += v[k];
        if (idx == NN - 1) off[NN] = run;  // == NE
    }
}

// bucket edges by target: srt[off[col]..off[col+1]) = source ids
__global__ void k_sort(const int* __restrict__ ei, int* __restrict__ cur,
                       int* __restrict__ srt) {
    int e = blockIdx.x * blockDim.x + threadIdx.x;
    if (e < NE) {
        int rw = ei[e], cl = ei[NE + e];
        int pos = atomicAdd(&cur[cl], 1);
        srt[pos] = rw;
    }
}

// h = x @ W^T  (into ws)
__global__ void k_linear(const float* __restrict__ x,
                         const float* __restrict__ W,
                         float* __restrict__ h) {
    __shared__ float Ws[C][C + 1];
    __shared__ float xs[8][C];
    int t = threadIdx.x;            // 0..255
    for (int i = t; i < C * C; i += 256)
        Ws[i / C][i % C] = W[i];

    int node0 = blockIdx.x * 8;
    int lnode = t >> 5;             // 0..7
    int cout  = t & 31;
    int node  = node0 + lnode;
    {
        int idx = node0 * C + t;    // coalesced load of 8 rows
        xs[lnode][cout] = (idx < NN * C) ? x[idx] : 0.0f;
    }
    __syncthreads();
    if (node < NN) {
        float s = 0.0f;
#pragma unroll
        for (int k = 0; k < C; ++k) s += xs[lnode][k] * Ws[cout][k];
        h[node * C + cout] = s;
    }
}

// one 64-lane wave per node: segmented sum over its bucketed edges,
// + bias + self-loop, single coalesced row store. No atomics.
__global__ __launch_bounds__(256) void k_agg(const int* __restrict__ off,
                                             const int* __restrict__ srt,
                                             const float* __restrict__ h,
                                             const float* __restrict__ dinv,
                                             const float* __restrict__ b,
                                             float* __restrict__ out) {
    int n = (blockIdx.x * blockDim.x + threadIdx.x) >> 6;
    if (n >= NN) return;
    int lane = threadIdx.x & 63;
    int c = lane & 31, p = lane >> 5;        // 2 edges in flight per wave
    int beg = off[n], end = off[n + 1];
    float s = 0.0f;
    for (int j = beg + p; j < end; j += 2) {
        int r = srt[j];                      // broadcast across 32 lanes
        s += h[r * C + c] * dinv[r];         // 128B coalesced row gather
    }
    s += __shfl_xor(s, 32);                  // combine p=0 / p=1 partials
    if (p == 0) {
        float dn = dinv[n];
        out[n * C + c] = b[c] + dn * (s + dn * h[n * C + c]);
    }
}

// ---------------- launch ----------------

extern "C" void kernel_launch(void* const* d_in, const int* in_sizes, int n_in,
                              void* d_out, int out_size, void* d_ws, size_t ws_size,
                              hipStream_t stream) {
    const float* x  = (const float*)d_in[0];
    const int*   ei = (const int*)d_in[1];
    const float* W  = (const float*)d_in[2];
    const float* b  = (const float*)d_in[3];
    float* out = (float*)d_out;

    // workspace layout (~20.8 MB), 256B-aligned slices
    char* ws = (char*)d_ws;
    size_t o = 0;
    float* h    = (float*)(ws + o); o += (size_t)NN * C * 4;      o = (o + 255) & ~(size_t)255;
    int*   cnt  = (int*)(ws + o);   o += (size_t)NN * 4;          o = (o + 255) & ~(size_t)255;
    int*   off  = (int*)(ws + o);   o += (size_t)(NN + 1) * 4;    o = (o + 255) & ~(size_t)255;
    int*   cur  = (int*)(ws + o);   o += (size_t)NN * 4;          o = (o + 255) & ~(size_t)255;
    float* dinv = (float*)(ws + o); o += (size_t)NN * 4;          o = (o + 255) & ~(size_t)255;
    int*   bsum = (int*)(ws + o);   o += (size_t)NSCB * 4;        o = (o + 255) & ~(size_t)255;
    int*   boff = (int*)(ws + o);   o += (size_t)NSCB * 4;        o = (o + 255) & ~(size_t)255;
    int*   srt  = (int*)(ws + o);

    k_zero<<<(NN + 255) / 256, 256, 0, stream>>>(cnt);
    k_hist<<<(NE + 255) / 256, 256, 0, stream>>>(ei, cnt);
    k_psum<<<NSCB, 256, 0, stream>>>(cnt, bsum);
    k_bscan<<<1, 64, 0, stream>>>(bsum, boff);
    k_fin<<<NSCB, 256, 0, stream>>>(cnt, boff, off, cur, dinv);
    k_sort<<<(NE + 255) / 256, 256, 0, stream>>>(ei, cur, srt);
    k_linear<<<(NN + 7) / 8, 256, 0, stream>>>(x, W, h);
    k_agg<<<(NN * 64 + 255) / 256, 256, 0, stream>>>(off, srt, h, dinv, b, out);
}